// Round 9
// baseline (1152.036 us; speedup 1.0000x reference)
//
#include <hip/hip_runtime.h>
#include <stdint.h>

// ============================================================================
// CPC forward on MI355X (gfx950).
// R2-R8 lesson: W_hh residency for a VALU (fdot2) GRU is impossible — arch
// VGPRs cap at 256/wave (the other 256 are AGPRs, not VALU-sourceable), and
// streaming W costs 384KB/CU/step on a ~128B/cyc load path (~328us floor).
// R9: MFMA-based GRU — MFMA can source AGPRs, so the full 512-reg unified
// file holds W as B-fragments. 8 blocks x 256 thr (4 waves, 1 wave/SIMD):
// wave owns 64 cols x 3 gates = 96 f16x8 B-frags (384 regs, AGPR-eligible);
// h tile (16x256) in LDS -> A-frags; 96 MFMA/step; gate math is lane-local
// (C-layout puts r,z,n of same (batch,col) in one lane). gx pre-swizzled to
// per-lane-contiguous by the gx GEMM; r/z biases folded into gx.
// ============================================================================

typedef _Float16 f16;
typedef __attribute__((ext_vector_type(2))) _Float16 f16x2;
typedef __attribute__((ext_vector_type(8))) _Float16 f16x8;
typedef __attribute__((ext_vector_type(4))) float f32x4;

__device__ __forceinline__ f16x2 u2h(unsigned int x) { return __builtin_bit_cast(f16x2, x); }
__device__ __forceinline__ float sigm_(float x) { return __builtin_amdgcn_rcpf(1.f + __expf(-x)); }
__device__ __forceinline__ float tanh_(float x) { return 1.f - 2.f * __builtin_amdgcn_rcpf(__expf(2.f * x) + 1.f); }

#define NTOT_LOSS 374784.0f  // 12 * 128 * 244

// ---------------------------------------------------------------------------
// K0: weight conversion/swizzles + combined bias + accumulator zeroing.
// whhG2: B-fragment-major W_hh: [wave 4][frag 96][lane 64][8 f16], where
//   frag = (g*4+nt)*8+ks; W row = g*256 + w*64 + nt*16 + (lane&15);
//   k = ks*32 + (lane>>4)*8 + e.  -> k_gru preload is 96 coalesced dwordx4.
// biasc[n] = b_ih[n] + (n<512 ? b_hh[n] : 0)   (n-gate b_hh can't fold: r*b).
// ---------------------------------------------------------------------------
__global__ void k_prep(const float* __restrict__ w1, const float* __restrict__ w2,
                       const float* __restrict__ wih, const float* __restrict__ whh,
                       const float* __restrict__ wkw, const float* __restrict__ bih,
                       const float* __restrict__ bhh,
                       f16* __restrict__ w1T, f16* __restrict__ w2T, f16* __restrict__ wihF,
                       f16* __restrict__ whhG2, f16* __restrict__ wkT,
                       float* __restrict__ biasc, float* __restrict__ accb) {
  const int stride = gridDim.x * blockDim.x;
  const int tid = blockIdx.x * blockDim.x + threadIdx.x;
  if (tid == 0) { accb[0] = 0.f; accb[1] = 0.f; }
  for (int i = tid; i < 768; i += stride) biasc[i] = bih[i] + (i < 512 ? bhh[i] : 0.f);
  // w1 (256k x 256n) -> w1T[n][k]
  for (int i = tid; i < 65536; i += stride) { int n = i >> 8, k = i & 255; w1T[i] = (f16)w1[k * 256 + n]; }
  // w2 (256k x 128n) -> w2T[n][k]
  for (int i = tid; i < 32768; i += stride) { int n = i >> 8, k = i & 255; w2T[i] = (f16)w2[k * 128 + n]; }
  // W_ih (768 x 128) already [N][K]
  for (int i = tid; i < 98304; i += stride) wihF[i] = (f16)wih[i];
  // W_hh -> whhG2 fragment-major
  for (int i = tid; i < 196608; i += stride) {
    const int e = i & 7, lane = (i >> 3) & 63, rest = i >> 9;
    const int w = rest / 96, fidx = rest % 96;
    const int ks = fidx & 7, gnt = fidx >> 3, g = gnt >> 2, nt = gnt & 3;
    const int row = g * 256 + w * 64 + nt * 16 + (lane & 15);
    const int k = ks * 32 + (lane >> 4) * 8 + e;
    whhG2[i] = (f16)whh[row * 256 + k];
  }
  // Wk_w (12,256c,128d) -> wkT[kk][d][c]
  for (int i = tid; i < 393216; i += stride) {
    int kk = i >> 15, rem = i & 32767, d = rem >> 8, c = rem & 255;
    wkT[i] = (f16)wkw[(kk << 15) + c * 128 + d];
  }
}

// ---------------------------------------------------------------------------
// Generic 64x64-tile f16 MFMA GEMM. GXS=true writes the k_gru gx swizzle:
// element (m,n) -> gxS[(((bc*256+t)*4 + wv)*64 + lane)*48 + slot].
// ---------------------------------------------------------------------------
template <int KTOT, bool AF32, bool RELU, bool GXS>
__global__ __launch_bounds__(256) void k_gemm64(const void* __restrict__ Aptr,
                                                const f16* __restrict__ BT,
                                                const float* __restrict__ bias,
                                                f16* __restrict__ out, const int NT) {
  __shared__ __align__(16) f16 Al[64][40];
  __shared__ __align__(16) f16 Bl[64][40];
  const int m0 = blockIdx.x * 64;
  const int n0 = blockIdx.y * 64;
  const int t = threadIdx.x;
  const int w = t >> 6, l = t & 63, lr = l & 15, lg = l >> 4;
  const int arow = t >> 2, akq = (t & 3) * 8;
  f32x4 acc[4] = {};
  for (int ks = 0; ks < KTOT / 32; ++ks) {
    const int kc = ks * 32;
    __syncthreads();
    if constexpr (AF32) {
      const float* src = (const float*)Aptr + (size_t)(m0 + arow) * KTOT + kc + akq;
      float4 v0 = *(const float4*)src;
      float4 v1 = *(const float4*)(src + 4);
      f16x8 hv = {(f16)v0.x, (f16)v0.y, (f16)v0.z, (f16)v0.w,
                  (f16)v1.x, (f16)v1.y, (f16)v1.z, (f16)v1.w};
      *(f16x8*)&Al[arow][akq] = hv;
    } else {
      const f16* src = (const f16*)Aptr + (size_t)(m0 + arow) * KTOT + kc + akq;
      *(f16x8*)&Al[arow][akq] = *(const f16x8*)src;
    }
    *(f16x8*)&Bl[arow][akq] = *(const f16x8*)(BT + (size_t)(n0 + arow) * KTOT + kc + akq);
    __syncthreads();
    f16x8 af = *(const f16x8*)&Al[16 * w + lr][lg * 8];
#pragma unroll
    for (int nt = 0; nt < 4; ++nt) {
      f16x8 bf = *(const f16x8*)&Bl[nt * 16 + lr][lg * 8];
      acc[nt] = __builtin_amdgcn_mfma_f32_16x16x32_f16(af, bf, acc[nt], 0, 0, 0);
    }
  }
#pragma unroll
  for (int nt = 0; nt < 4; ++nt) {
    const int n = n0 + nt * 16 + lr;
    const float bb = bias[n];
#pragma unroll
    for (int r = 0; r < 4; ++r) {
      const int m = m0 + 16 * w + lg * 4 + r;
      float v = acc[nt][r] + bb;
      if (RELU) v = fmaxf(v, 0.f);
      if constexpr (GXS) {
        const int b = m >> 8, tt2 = m & 255, bc = b >> 4, ml = b & 15;
        const int g = n >> 8, col = n & 255;
        const int wv = col >> 6, nt2 = (col >> 4) & 3, cl2 = col & 15;
        const int lane2 = ((ml >> 2) << 4) | cl2;
        const int slot = g * 16 + nt2 * 4 + (ml & 3);
        out[((((size_t)bc * 256 + tt2) * 4 + wv) * 64 + lane2) * 48 + slot] = (f16)v;
      } else {
        out[(size_t)m * NT + n] = (f16)v;
      }
    }
  }
}

// ---------------------------------------------------------------------------
// K2: z = l2norm(h1 @ w2T + b2). Writes z f32 (output) + z f16 (workspace).
// ---------------------------------------------------------------------------
__global__ __launch_bounds__(256) void k_enc2(const f16* __restrict__ A, const f16* __restrict__ BT,
                                              const float* __restrict__ bias,
                                              float* __restrict__ zf32, f16* __restrict__ zf16) {
  __shared__ __align__(16) f16 Al[64][40];
  __shared__ __align__(16) f16 Bl[128][40];
  const int m0 = blockIdx.x * 64;
  const int t = threadIdx.x;
  const int w = t >> 6, l = t & 63, lr = l & 15, lg = l >> 4;
  const int arow = t >> 2, akq = (t & 3) * 8;
  f32x4 acc[8] = {};
  for (int ks = 0; ks < 8; ++ks) {
    const int kc = ks * 32;
    __syncthreads();
    *(f16x8*)&Al[arow][akq] = *(const f16x8*)(A + (size_t)(m0 + arow) * 256 + kc + akq);
#pragma unroll
    for (int hh = 0; hh < 2; ++hh) {
      const int brow = arow + 64 * hh;
      *(f16x8*)&Bl[brow][akq] = *(const f16x8*)(BT + (size_t)brow * 256 + kc + akq);
    }
    __syncthreads();
    f16x8 af = *(const f16x8*)&Al[16 * w + lr][lg * 8];
#pragma unroll
    for (int nt = 0; nt < 8; ++nt) {
      f16x8 bf = *(const f16x8*)&Bl[nt * 16 + lr][lg * 8];
      acc[nt] = __builtin_amdgcn_mfma_f32_16x16x32_f16(af, bf, acc[nt], 0, 0, 0);
    }
  }
  float v[8][4];
#pragma unroll
  for (int nt = 0; nt < 8; ++nt) {
    const float bb = bias[nt * 16 + lr];
#pragma unroll
    for (int r = 0; r < 4; ++r) v[nt][r] = acc[nt][r] + bb;
  }
#pragma unroll
  for (int r = 0; r < 4; ++r) {
    float ss = 0.f;
#pragma unroll
    for (int nt = 0; nt < 8; ++nt) ss += v[nt][r] * v[nt][r];
    ss += __shfl_xor(ss, 1); ss += __shfl_xor(ss, 2); ss += __shfl_xor(ss, 4); ss += __shfl_xor(ss, 8);
    const float scl = 1.f / fmaxf(sqrtf(ss), 1e-12f);
    const int m = m0 + 16 * w + lg * 4 + r;
#pragma unroll
    for (int nt = 0; nt < 8; ++nt) {
      const int n = nt * 16 + lr;
      const float z = v[nt][r] * scl;
      zf32[(size_t)m * 128 + n] = z;
      zf16[(size_t)m * 128 + n] = (f16)z;
    }
  }
}

// ---------------------------------------------------------------------------
// K4: MFMA GRU scan. 8 blocks (16 batch rows each) x 256 threads (4 waves,
// 1 wave/SIMD -> full 512-reg unified budget). Wave w owns cols [64w,64w+64)
// of all 3 gates: 96 B-frags (f16x8) = 384 regs, MFMA-sourceable from AGPR.
// h tile [16][256] f16 double-buffered in LDS. Per step: 8 ksteps x 12 MFMA,
// then lane-local gates (C-layout: lane&15=col-in-tile, 4*(lane>>4)+i=batch).
// ---------------------------------------------------------------------------
__global__ __attribute__((amdgpu_flat_work_group_size(256, 256), amdgpu_waves_per_eu(1, 1)))
void k_gru(const f16* __restrict__ gxS, const f16* __restrict__ whhG2,
           const float* __restrict__ bhh, f16* __restrict__ cf16) {
  __shared__ __align__(16) f16 h_lds[2][16][264];
  const int bc = blockIdx.x;
  const int t = threadIdx.x;
  const int w = t >> 6, lane = t & 63;
  const int hi = lane >> 4, cl = lane & 15;
  // ---- preload 96 W B-frags (coalesced: 1KB per frag per wave) ----
  f16x8 Wf[96];
  {
    const f16* base = whhG2 + ((size_t)w * 96) * 512 + (size_t)lane * 8;
#pragma unroll
    for (int f = 0; f < 96; ++f) Wf[f] = *(const f16x8*)(base + (size_t)f * 512);
  }
  // n-gate b_hh (not foldable into gx: multiplied by r)
  float bhn[4];
#pragma unroll
  for (int nt = 0; nt < 4; ++nt) bhn[nt] = bhh[512 + 64 * w + nt * 16 + cl];
  // zero h buffer 0
  for (int idx = t; idx < 16 * 264; idx += 256) h_lds[0][idx / 264][idx % 264] = (f16)0.f;
  const f16* gxp = gxS + ((((size_t)bc * 256) * 4 + w) * 64 + lane) * 48;
  f16* cfb = cf16 + ((size_t)(bc * 16 + 4 * hi) << 16) + 64 * w + cl;
  __syncthreads();
#pragma unroll 1
  for (int tt = 0; tt < 256; ++tt) {
    const int cur = tt & 1;
    // gx prefetch: 48 f16 contiguous per lane
    const f16* gxt = gxp + (size_t)tt * 12288;
    uint4 gxv[6];
#pragma unroll
    for (int j = 0; j < 6; ++j) gxv[j] = *(const uint4*)(gxt + j * 8);
    // previous h for this lane's 16 (m,col) outputs
    f16 hold[4][4];
#pragma unroll
    for (int nt = 0; nt < 4; ++nt)
#pragma unroll
      for (int i = 0; i < 4; ++i)
        hold[nt][i] = h_lds[cur][4 * hi + i][64 * w + nt * 16 + cl];
    // ---- 96 MFMA: acc[g*4+nt] over 8 ksteps ----
    f32x4 acc[12] = {};
#pragma unroll
    for (int ks = 0; ks < 8; ++ks) {
      const f16x8 af = *(const f16x8*)&h_lds[cur][cl][ks * 32 + hi * 8];
#pragma unroll
      for (int gn = 0; gn < 12; ++gn)
        acc[gn] = __builtin_amdgcn_mfma_f32_16x16x32_f16(af, Wf[gn * 8 + ks], acc[gn], 0, 0, 0);
    }
    // ---- lane-local gates ----
#pragma unroll
    for (int nt = 0; nt < 4; ++nt) {
#pragma unroll
      for (int i = 0; i < 4; ++i) {
        const int sr = nt * 4 + i, sz = 16 + nt * 4 + i, sn = 32 + nt * 4 + i;
        const float xr = (float)u2h(gxv[sr >> 3][(sr >> 1) & 3])[sr & 1];
        const float xz = (float)u2h(gxv[sz >> 3][(sz >> 1) & 3])[sz & 1];
        const float xn = (float)u2h(gxv[sn >> 3][(sn >> 1) & 3])[sn & 1];
        const float r = sigm_(xr + acc[nt][i]);          // b_ih+b_hh in gx
        const float z = sigm_(xz + acc[4 + nt][i]);
        const float n = tanh_(xn + r * (acc[8 + nt][i] + bhn[nt]));
        const float h = (1.f - z) * n + z * (float)hold[nt][i];
        const f16 hh = (f16)h;
        h_lds[cur ^ 1][4 * hi + i][64 * w + nt * 16 + cl] = hh;
        cfb[((size_t)i << 16) + (size_t)tt * 256 + nt * 16] = hh;
      }
    }
    __syncthreads();
  }
}

// ---------------------------------------------------------------------------
// K4b: c_seq f32 output = widen cf16.
// ---------------------------------------------------------------------------
__global__ void k_c32(const f16* __restrict__ cf, float* __restrict__ o) {
  const size_t i = (size_t)(blockIdx.x * blockDim.x + threadIdx.x) * 8;
  const f16x8 v = *(const f16x8*)(cf + i);
  float4 a = {(float)v[0], (float)v[1], (float)v[2], (float)v[3]};
  float4 b = {(float)v[4], (float)v[5], (float)v[6], (float)v[7]};
  *(float4*)(o + i) = a;
  *(float4*)(o + i + 4) = b;
}

// ---------------------------------------------------------------------------
// K5: fused preds -> l2norm -> logits -> online LSE / pos / neg-max -> loss&acc.
// ---------------------------------------------------------------------------
__global__ __launch_bounds__(256) void k_cpc(const f16* __restrict__ cf16, const f16* __restrict__ zf16,
                                             const f16* __restrict__ wkT, const float* __restrict__ wkb,
                                             float* __restrict__ accb) {
  __shared__ __align__(16) f16 SMc[64 * 264];
  __shared__ __align__(16) f16 Bl[128][40];
  __shared__ __align__(16) f16 P[64][136];
  __shared__ float red[2];
  const int tc = blockIdx.x, b = blockIdx.y, kk = blockIdx.z;
  const int t0 = tc * 64;
  const int t = threadIdx.x;
  const int w = t >> 6, l = t & 63, lr = l & 15, lg = l >> 4;
  {
    const uint32_t* src = (const uint32_t*)(cf16 + ((size_t)b * 256 + t0) * 256);
    uint32_t* dst = (uint32_t*)SMc;
#pragma unroll
    for (int it = 0; it < 32; ++it) {
      const int idx = it * 256 + t, row = idx >> 7, cw = idx & 127;
      dst[row * 132 + cw] = src[row * 128 + cw];
    }
  }
  f32x4 acc[8] = {};
  for (int ks = 0; ks < 8; ++ks) {
    __syncthreads();
    {
      const uint32_t* bsrc = (const uint32_t*)(wkT + ((size_t)kk << 15));
      uint32_t* bd = (uint32_t*)Bl;
#pragma unroll
      for (int it = 0; it < 8; ++it) {
        const int idx = it * 256 + t, row = idx >> 4, kw = idx & 15;
        bd[row * 20 + kw] = bsrc[row * 128 + ks * 16 + kw];
      }
    }
    __syncthreads();
    f16x8 af = *(const f16x8*)&SMc[(16 * w + lr) * 264 + ks * 32 + lg * 8];
#pragma unroll
    for (int nt = 0; nt < 8; ++nt) {
      f16x8 bf = *(const f16x8*)&Bl[nt * 16 + lr][lg * 8];
      acc[nt] = __builtin_amdgcn_mfma_f32_16x16x32_f16(af, bf, acc[nt], 0, 0, 0);
    }
  }
  {
    float v[8][4];
#pragma unroll
    for (int nt = 0; nt < 8; ++nt) {
      const float bb = wkb[kk * 128 + nt * 16 + lr];
#pragma unroll
      for (int r = 0; r < 4; ++r) v[nt][r] = acc[nt][r] + bb;
    }
#pragma unroll
    for (int r = 0; r < 4; ++r) {
      float ss = 0.f;
#pragma unroll
      for (int nt = 0; nt < 8; ++nt) ss += v[nt][r] * v[nt][r];
      ss += __shfl_xor(ss, 1); ss += __shfl_xor(ss, 2); ss += __shfl_xor(ss, 4); ss += __shfl_xor(ss, 8);
      const float scl = 1.f / fmaxf(sqrtf(ss), 1e-12f);
#pragma unroll
      for (int nt = 0; nt < 8; ++nt)
        P[16 * w + lg * 4 + r][nt * 16 + lr] = (f16)(v[nt][r] * scl);
    }
  }
  __syncthreads();
  float m_run[4], s_run[4], pos_v[4], neg_m[4];
#pragma unroll
  for (int r = 0; r < 4; ++r) { m_run[r] = -1e30f; s_run[r] = 0.f; pos_v[r] = -1e30f; neg_m[r] = -1e30f; }
  for (int sc = 0; sc < 4; ++sc) {
    __syncthreads();
    {
      const uint32_t* zsrc = (const uint32_t*)(zf16 + ((size_t)b * 256 + sc * 64) * 128);
      uint32_t* zd = (uint32_t*)SMc;
#pragma unroll
      for (int it = 0; it < 16; ++it) {
        const int idx = it * 256 + t, row = idx >> 6, cw = idx & 63;
        zd[row * 68 + cw] = zsrc[row * 64 + cw];
      }
    }
    __syncthreads();
    f32x4 sa[4] = {};
#pragma unroll
    for (int ks = 0; ks < 4; ++ks) {
      f16x8 af = *(const f16x8*)&P[16 * w + lr][ks * 32 + lg * 8];
#pragma unroll
      for (int nt = 0; nt < 4; ++nt) {
        f16x8 bf = *(const f16x8*)&SMc[(nt * 16 + lr) * 136 + ks * 32 + lg * 8];
        sa[nt] = __builtin_amdgcn_mfma_f32_16x16x32_f16(af, bf, sa[nt], 0, 0, 0);
      }
    }
#pragma unroll
    for (int r = 0; r < 4; ++r) {
      const int trow = t0 + 16 * w + lg * 4 + r;
      const int pos_s = trow + kk + 1;
      float vv[4];
#pragma unroll
      for (int nt = 0; nt < 4; ++nt) vv[nt] = sa[nt][r] * 10.f;
      float cm = fmaxf(fmaxf(vv[0], vv[1]), fmaxf(vv[2], vv[3]));
      cm = fmaxf(cm, __shfl_xor(cm, 1)); cm = fmaxf(cm, __shfl_xor(cm, 2));
      cm = fmaxf(cm, __shfl_xor(cm, 4)); cm = fmaxf(cm, __shfl_xor(cm, 8));
      const float nm = fmaxf(m_run[r], cm);
      float ps = __expf(vv[0] - nm) + __expf(vv[1] - nm) + __expf(vv[2] - nm) + __expf(vv[3] - nm);
      ps += __shfl_xor(ps, 1); ps += __shfl_xor(ps, 2); ps += __shfl_xor(ps, 4); ps += __shfl_xor(ps, 8);
      s_run[r] = s_run[r] * __expf(m_run[r] - nm) + ps;
      m_run[r] = nm;
      const int sbase = sc * 64 + lr;
#pragma unroll
      for (int nt = 0; nt < 4; ++nt) {
        const int s = sbase + nt * 16;
        if (s == pos_s) pos_v[r] = vv[nt];
        else neg_m[r] = fmaxf(neg_m[r], vv[nt]);
      }
    }
  }
  __syncthreads();
  if (t == 0) { red[0] = 0.f; red[1] = 0.f; }
  __syncthreads();
  float lsum = 0.f, csum = 0.f;
#pragma unroll
  for (int r = 0; r < 4; ++r) {
    float pv = pos_v[r], ng = neg_m[r];
    pv = fmaxf(pv, __shfl_xor(pv, 1)); pv = fmaxf(pv, __shfl_xor(pv, 2));
    pv = fmaxf(pv, __shfl_xor(pv, 4)); pv = fmaxf(pv, __shfl_xor(pv, 8));
    ng = fmaxf(ng, __shfl_xor(ng, 1)); ng = fmaxf(ng, __shfl_xor(ng, 2));
    ng = fmaxf(ng, __shfl_xor(ng, 4)); ng = fmaxf(ng, __shfl_xor(ng, 8));
    const int trow = t0 + 16 * w + lg * 4 + r;
    if (lr == 0 && trow < 244) {
      const float lse = m_run[r] + __logf(s_run[r]);
      lsum += lse - pv;
      csum += (pv >= ng) ? 1.f : 0.f;
    }
  }
  if (lr == 0) { atomicAdd(&red[0], lsum); atomicAdd(&red[1], csum); }
  __syncthreads();
  if (t == 0) { atomicAdd(&accb[0], red[0]); atomicAdd(&accb[1], red[1]); }
}

__global__ void k_fin(const float* __restrict__ accb, float* __restrict__ out) {
  out[0] = accb[0] * (1.0f / NTOT_LOSS);
  out[1] = accb[1] * (100.0f / NTOT_LOSS);
}

// ---------------------------------------------------------------------------
extern "C" void kernel_launch(void* const* d_in, const int* in_sizes, int n_in,
                              void* d_out, int out_size, void* d_ws, size_t ws_size,
                              hipStream_t stream) {
  (void)in_sizes; (void)n_in; (void)out_size; (void)ws_size;
  const float* rr  = (const float*)d_in[0];
  const float* w1  = (const float*)d_in[1];
  const float* b1  = (const float*)d_in[2];
  const float* w2  = (const float*)d_in[3];
  const float* b2  = (const float*)d_in[4];
  const float* wih = (const float*)d_in[5];
  const float* whh = (const float*)d_in[6];
  const float* bih = (const float*)d_in[7];
  const float* bhh = (const float*)d_in[8];
  const float* wkw = (const float*)d_in[9];
  const float* wkb = (const float*)d_in[10];
  float* out = (float*)d_out;
  char* ws = (char*)d_ws;

  const size_t GX_B = (size_t)32768 * 768 * 2;  // 50,331,648 (gxS, same size)
  f16* gxS  = (f16*)ws;
  f16* h1   = (f16*)ws;  // alias: h1 dead before gxS written
  f16* zf16 = (f16*)(ws + GX_B);
  f16* cf16 = (f16*)(ws + GX_B + 8388608);
  f16* w1T  = (f16*)(ws + GX_B + 8388608 + 16777216);
  f16* w2T  = w1T + 65536;
  f16* wihF = w2T + 32768;
  f16* whhG2 = wihF + 98304;
  f16* wkT  = whhG2 + 196608;
  float* biasc = (float*)(wkT + 393216);
  float* accb  = biasc + 768;

  float* zf32 = out + 2;
  float* cf32 = out + 2 + 4194304;

  k_prep<<<256, 256, 0, stream>>>(w1, w2, wih, whh, wkw, bih, bhh,
                                  w1T, w2T, wihF, whhG2, wkT, biasc, accb);
  k_gemm64<256, true, true, false><<<dim3(512, 4), 256, 0, stream>>>(rr, w1T, b1, h1, 256);
  k_enc2<<<dim3(512), 256, 0, stream>>>(h1, w2T, b2, zf32, zf16);
  k_gemm64<128, false, false, true><<<dim3(512, 12), 256, 0, stream>>>(zf16, wihF, biasc, gxS, 768);
  k_gru<<<8, 256, 0, stream>>>(gxS, whhG2, bhh, cf16);
  k_c32<<<4096, 256, 0, stream>>>(cf16, cf32);
  k_cpc<<<dim3(4, 128, 12), 256, 0, stream>>>(cf16, zf16, wkT, wkb, accb);
  k_fin<<<1, 1, 0, stream>>>(accb, out);
}

// Round 10
// 842.507 us; speedup vs baseline: 1.3674x; 1.3674x over previous
//
#include <hip/hip_runtime.h>
#include <stdint.h>

// ============================================================================
// CPC forward on MI355X (gfx950).
// R9 lesson: MFMA-GRU with W in the unified reg file WORKS (no spill, VGPR
// 240), but 1 wave/SIMD latency-serialized everything (6600 cyc/step).
// R10: 8 blocks x 512 threads (2 waves/SIMD): wave owns 32 h-cols x 3 gates
// = 48 B-frags (192 regs, AGPR-eligible, <=256/wave cap). MFMA of one wave
// overlaps gate-VALU of the other (separate pipes). h_own in regs; gx load
// issued at step top (hidden under MFMA); cf16 t-major so stores are
// base+imm; one barrier/step. Target ~1050 cyc/step -> ~112us.
// ============================================================================

typedef _Float16 f16;
typedef __attribute__((ext_vector_type(2))) _Float16 f16x2;
typedef __attribute__((ext_vector_type(8))) _Float16 f16x8;
typedef __attribute__((ext_vector_type(4))) float f32x4;

__device__ __forceinline__ f16x2 u2h(unsigned int x) { return __builtin_bit_cast(f16x2, x); }
__device__ __forceinline__ float sigm_(float x) { return __builtin_amdgcn_rcpf(1.f + __expf(-x)); }
__device__ __forceinline__ float tanh_(float x) { return 1.f - 2.f * __builtin_amdgcn_rcpf(__expf(2.f * x) + 1.f); }
// compile-time slot extract from 3 packed uint4 (s in [0,24))
__device__ __forceinline__ float gxe(const uint4& a, const uint4& b, const uint4& c, int s) {
  const uint4 v = (s < 8) ? a : (s < 16) ? b : c;
  const int r = s & 7;
  const unsigned d = (r < 2) ? v.x : (r < 4) ? v.y : (r < 6) ? v.z : v.w;
  return (float)u2h(d)[s & 1];
}

#define NTOT_LOSS 374784.0f  // 12 * 128 * 244

// ---------------------------------------------------------------------------
// K0: weight conversion/swizzles + combined bias + accumulator zeroing.
// whhG3: [w 8][f 48][lane 64][e 8]; f=(g*2+nt)*8+ks; row=256g+32w+16nt+(lane&15);
//        k=32ks+8*(lane>>4)+e.  biasc[n]=b_ih[n]+(n<512?b_hh[n]:0).
// ---------------------------------------------------------------------------
__global__ void k_prep(const float* __restrict__ w1, const float* __restrict__ w2,
                       const float* __restrict__ wih, const float* __restrict__ whh,
                       const float* __restrict__ wkw, const float* __restrict__ bih,
                       const float* __restrict__ bhh,
                       f16* __restrict__ w1T, f16* __restrict__ w2T, f16* __restrict__ wihF,
                       f16* __restrict__ whhG3, f16* __restrict__ wkT,
                       float* __restrict__ biasc, float* __restrict__ accb) {
  const int stride = gridDim.x * blockDim.x;
  const int tid = blockIdx.x * blockDim.x + threadIdx.x;
  if (tid == 0) { accb[0] = 0.f; accb[1] = 0.f; }
  for (int i = tid; i < 768; i += stride) biasc[i] = bih[i] + (i < 512 ? bhh[i] : 0.f);
  for (int i = tid; i < 65536; i += stride) { int n = i >> 8, k = i & 255; w1T[i] = (f16)w1[k * 256 + n]; }
  for (int i = tid; i < 32768; i += stride) { int n = i >> 8, k = i & 255; w2T[i] = (f16)w2[k * 128 + n]; }
  for (int i = tid; i < 98304; i += stride) wihF[i] = (f16)wih[i];
  // W_hh -> whhG3 fragment-major
  for (int i = tid; i < 196608; i += stride) {
    const int e = i & 7, lane = (i >> 3) & 63, rest = i >> 9;       // rest = w*48+f
    const int w = rest / 48, f = rest % 48;
    const int ks = f & 7, gnt = f >> 3, g = gnt >> 1, nt = gnt & 1;
    const int cl = lane & 15, hi = lane >> 4;
    const int row = g * 256 + w * 32 + nt * 16 + cl;
    const int k = ks * 32 + hi * 8 + e;
    whhG3[i] = (f16)whh[row * 256 + k];
  }
  for (int i = tid; i < 393216; i += stride) {
    int kk = i >> 15, rem = i & 32767, d = rem >> 8, c = rem & 255;
    wkT[i] = (f16)wkw[(kk << 15) + c * 128 + d];
  }
}

// ---------------------------------------------------------------------------
// Generic 64x64-tile f16 MFMA GEMM. GXS=true writes the k_gru gx swizzle.
// ---------------------------------------------------------------------------
template <int KTOT, bool AF32, bool RELU, bool GXS>
__global__ __launch_bounds__(256) void k_gemm64(const void* __restrict__ Aptr,
                                                const f16* __restrict__ BT,
                                                const float* __restrict__ bias,
                                                f16* __restrict__ out, const int NT) {
  __shared__ __align__(16) f16 Al[64][40];
  __shared__ __align__(16) f16 Bl[64][40];
  const int m0 = blockIdx.x * 64;
  const int n0 = blockIdx.y * 64;
  const int t = threadIdx.x;
  const int w = t >> 6, l = t & 63, lr = l & 15, lg = l >> 4;
  const int arow = t >> 2, akq = (t & 3) * 8;
  f32x4 acc[4] = {};
  for (int ks = 0; ks < KTOT / 32; ++ks) {
    const int kc = ks * 32;
    __syncthreads();
    if constexpr (AF32) {
      const float* src = (const float*)Aptr + (size_t)(m0 + arow) * KTOT + kc + akq;
      float4 v0 = *(const float4*)src;
      float4 v1 = *(const float4*)(src + 4);
      f16x8 hv = {(f16)v0.x, (f16)v0.y, (f16)v0.z, (f16)v0.w,
                  (f16)v1.x, (f16)v1.y, (f16)v1.z, (f16)v1.w};
      *(f16x8*)&Al[arow][akq] = hv;
    } else {
      const f16* src = (const f16*)Aptr + (size_t)(m0 + arow) * KTOT + kc + akq;
      *(f16x8*)&Al[arow][akq] = *(const f16x8*)src;
    }
    *(f16x8*)&Bl[arow][akq] = *(const f16x8*)(BT + (size_t)(n0 + arow) * KTOT + kc + akq);
    __syncthreads();
    f16x8 af = *(const f16x8*)&Al[16 * w + lr][lg * 8];
#pragma unroll
    for (int nt = 0; nt < 4; ++nt) {
      f16x8 bf = *(const f16x8*)&Bl[nt * 16 + lr][lg * 8];
      acc[nt] = __builtin_amdgcn_mfma_f32_16x16x32_f16(af, bf, acc[nt], 0, 0, 0);
    }
  }
#pragma unroll
  for (int nt = 0; nt < 4; ++nt) {
    const int n = n0 + nt * 16 + lr;
    const float bb = bias[n];
#pragma unroll
    for (int r = 0; r < 4; ++r) {
      const int m = m0 + 16 * w + lg * 4 + r;
      float v = acc[nt][r] + bb;
      if (RELU) v = fmaxf(v, 0.f);
      if constexpr (GXS) {
        // (m,n) -> gxS[(((bc*256+tt)*8 + w2)*64 + lane2)*24 + slot]
        const int b = m >> 8, tt2 = m & 255;
        const int bc = b >> 4, ml = b & 15, hi2 = ml >> 2, i2 = ml & 3;
        const int g = n >> 8, col = n & 255;
        const int w2 = col >> 5, nt2 = (col >> 4) & 1, cl2 = col & 15;
        const int lane2 = hi2 * 16 + cl2;
        const int slot = (g * 2 + nt2) * 4 + i2;
        out[((((size_t)bc * 256 + tt2) * 8 + w2) * 64 + lane2) * 24 + slot] = (f16)v;
      } else {
        out[(size_t)m * NT + n] = (f16)v;
      }
    }
  }
}

// ---------------------------------------------------------------------------
// K2: z = l2norm(h1 @ w2T + b2). Writes z f32 (output) + z f16 (workspace).
// ---------------------------------------------------------------------------
__global__ __launch_bounds__(256) void k_enc2(const f16* __restrict__ A, const f16* __restrict__ BT,
                                              const float* __restrict__ bias,
                                              float* __restrict__ zf32, f16* __restrict__ zf16) {
  __shared__ __align__(16) f16 Al[64][40];
  __shared__ __align__(16) f16 Bl[128][40];
  const int m0 = blockIdx.x * 64;
  const int t = threadIdx.x;
  const int w = t >> 6, l = t & 63, lr = l & 15, lg = l >> 4;
  const int arow = t >> 2, akq = (t & 3) * 8;
  f32x4 acc[8] = {};
  for (int ks = 0; ks < 8; ++ks) {
    const int kc = ks * 32;
    __syncthreads();
    *(f16x8*)&Al[arow][akq] = *(const f16x8*)(A + (size_t)(m0 + arow) * 256 + kc + akq);
#pragma unroll
    for (int hh = 0; hh < 2; ++hh) {
      const int brow = arow + 64 * hh;
      *(f16x8*)&Bl[brow][akq] = *(const f16x8*)(BT + (size_t)brow * 256 + kc + akq);
    }
    __syncthreads();
    f16x8 af = *(const f16x8*)&Al[16 * w + lr][lg * 8];
#pragma unroll
    for (int nt = 0; nt < 8; ++nt) {
      f16x8 bf = *(const f16x8*)&Bl[nt * 16 + lr][lg * 8];
      acc[nt] = __builtin_amdgcn_mfma_f32_16x16x32_f16(af, bf, acc[nt], 0, 0, 0);
    }
  }
  float v[8][4];
#pragma unroll
  for (int nt = 0; nt < 8; ++nt) {
    const float bb = bias[nt * 16 + lr];
#pragma unroll
    for (int r = 0; r < 4; ++r) v[nt][r] = acc[nt][r] + bb;
  }
#pragma unroll
  for (int r = 0; r < 4; ++r) {
    float ss = 0.f;
#pragma unroll
    for (int nt = 0; nt < 8; ++nt) ss += v[nt][r] * v[nt][r];
    ss += __shfl_xor(ss, 1); ss += __shfl_xor(ss, 2); ss += __shfl_xor(ss, 4); ss += __shfl_xor(ss, 8);
    const float scl = 1.f / fmaxf(sqrtf(ss), 1e-12f);
    const int m = m0 + 16 * w + lg * 4 + r;
#pragma unroll
    for (int nt = 0; nt < 8; ++nt) {
      const int n = nt * 16 + lr;
      const float z = v[nt][r] * scl;
      zf32[(size_t)m * 128 + n] = z;
      zf16[(size_t)m * 128 + n] = (f16)z;
    }
  }
}

// ---------------------------------------------------------------------------
// K4: MFMA GRU scan. 8 blocks x 512 threads (8 waves, 2/SIMD). Wave w owns
// h-cols [32w,32w+32) x 3 gates: 48 B-frags (192 regs). Per step: 48 MFMA,
// lane-local gates for 8 outputs (2 nt x 4 batches), h_own in regs,
// cf16 t-major [t][b][c] so stores fold to base+imm. One barrier/step.
// ---------------------------------------------------------------------------
__global__ __attribute__((amdgpu_flat_work_group_size(512, 512)))
void k_gru(const f16* __restrict__ gxS, const f16* __restrict__ whhG3,
           const float* __restrict__ bhh, f16* __restrict__ cf16) {
  __shared__ __align__(16) f16 h_lds[2][16][264];
  const int bc = blockIdx.x;
  const int t = threadIdx.x;
  const int w = t >> 6, lane = t & 63;
  const int hi = lane >> 4, cl = lane & 15;
  // ---- preload 48 W B-frags (coalesced) ----
  f16x8 Wf[48];
  {
    const f16* base = whhG3 + (size_t)w * 24576 + (size_t)lane * 8;
#pragma unroll
    for (int f = 0; f < 48; ++f) Wf[f] = *(const f16x8*)(base + (size_t)f * 512);
  }
  const float bhn0 = bhh[512 + w * 32 + cl];
  const float bhn1 = bhh[512 + w * 32 + 16 + cl];
  // zero h buffer 0 (8448 f16 = 4224 u32)
  for (int idx = t; idx < 4224; idx += 512) ((uint32_t*)h_lds)[idx] = 0u;
  float ho[2][4] = {};
  const f16* gxp = gxS + (((size_t)bc * 256 * 8 + w) * 64 + lane) * 24;
  f16* cfb = cf16 + ((size_t)(16 * bc + 4 * hi)) * 256 + w * 32 + cl;
  __syncthreads();
#pragma unroll 1
  for (int tt = 0; tt < 256; ++tt) {
    const int cur = tt & 1;
    // gx loads issued first; consumed ~600cyc later (hidden under MFMA)
    const f16* gxt = gxp + (size_t)tt * 12288;
    const uint4 gA = *(const uint4*)(gxt);
    const uint4 gB = *(const uint4*)(gxt + 8);
    const uint4 gC = *(const uint4*)(gxt + 16);
    // ---- 48 MFMA: acc[g*2+nt] over 8 ksteps ----
    f32x4 acc[6] = {};
#pragma unroll
    for (int ks = 0; ks < 8; ++ks) {
      const f16x8 af = *(const f16x8*)&h_lds[cur][cl][ks * 32 + hi * 8];
#pragma unroll
      for (int gn = 0; gn < 6; ++gn)
        acc[gn] = __builtin_amdgcn_mfma_f32_16x16x32_f16(af, Wf[gn * 8 + ks], acc[gn], 0, 0, 0);
    }
    // ---- lane-local gates: 8 outputs = 2 nt x 4 batches ----
    f16* hb = &h_lds[cur ^ 1][0][0];
    f16* cfo = cfb + (size_t)tt * 32768;
#pragma unroll
    for (int nt = 0; nt < 2; ++nt) {
      const float bhn = nt ? bhn1 : bhn0;
#pragma unroll
      for (int i = 0; i < 4; ++i) {
        const float xr = gxe(gA, gB, gC, (0 + nt) * 4 + i);
        const float xz = gxe(gA, gB, gC, (2 + nt) * 4 + i);
        const float xn = gxe(gA, gB, gC, (4 + nt) * 4 + i);
        const float r = sigm_(xr + acc[nt][i]);          // b_ih+b_hh folded in gx
        const float z = sigm_(xz + acc[2 + nt][i]);
        const float n = tanh_(xn + r * (acc[4 + nt][i] + bhn));
        const float h = (1.f - z) * n + z * ho[nt][i];
        ho[nt][i] = h;
        const f16 hh = (f16)h;
        hb[(4 * hi + i) * 264 + w * 32 + nt * 16 + cl] = hh;
        cfo[i * 256 + nt * 16] = hh;                     // imm offsets
      }
    }
    __syncthreads();
  }
}

// ---------------------------------------------------------------------------
// K4b: c_seq f32 output = widen + transpose cf16[t][b][c] -> cf32[b][t][c].
// ---------------------------------------------------------------------------
__global__ void k_c32(const f16* __restrict__ cf, float* __restrict__ o) {
  const size_t idx = (size_t)(blockIdx.x * blockDim.x + threadIdx.x) * 8;
  const int c = idx & 255;
  const int b = (idx >> 8) & 127;
  const int t2 = idx >> 15;
  const f16x8 v = *(const f16x8*)(cf + ((size_t)t2 * 128 + b) * 256 + c);
  float* op = o + ((size_t)b * 256 + t2) * 256 + c;
  float4 a = {(float)v[0], (float)v[1], (float)v[2], (float)v[3]};
  float4 bb = {(float)v[4], (float)v[5], (float)v[6], (float)v[7]};
  *(float4*)op = a;
  *(float4*)(op + 4) = bb;
}

// ---------------------------------------------------------------------------
// K5: fused preds -> l2norm -> logits -> online LSE / pos / neg-max -> loss&acc.
// cf16 is t-major: row r of the c-tile lives at cf16[(t0+r)*128 + b][*].
// ---------------------------------------------------------------------------
__global__ __launch_bounds__(256) void k_cpc(const f16* __restrict__ cf16, const f16* __restrict__ zf16,
                                             const f16* __restrict__ wkT, const float* __restrict__ wkb,
                                             float* __restrict__ accb) {
  __shared__ __align__(16) f16 SMc[64 * 264];
  __shared__ __align__(16) f16 Bl[128][40];
  __shared__ __align__(16) f16 P[64][136];
  __shared__ float red[2];
  const int tc = blockIdx.x, b = blockIdx.y, kk = blockIdx.z;
  const int t0 = tc * 64;
  const int t = threadIdx.x;
  const int w = t >> 6, l = t & 63, lr = l & 15, lg = l >> 4;
  {
    const uint32_t* srcu = (const uint32_t*)cf16 + (size_t)t0 * 16384 + (size_t)b * 128;
    uint32_t* dst = (uint32_t*)SMc;
#pragma unroll
    for (int it = 0; it < 32; ++it) {
      const int idx = it * 256 + t, row = idx >> 7, cw = idx & 127;
      dst[row * 132 + cw] = srcu[(size_t)row * 16384 + cw];
    }
  }
  f32x4 acc[8] = {};
  for (int ks = 0; ks < 8; ++ks) {
    __syncthreads();
    {
      const uint32_t* bsrc = (const uint32_t*)(wkT + ((size_t)kk << 15));
      uint32_t* bd = (uint32_t*)Bl;
#pragma unroll
      for (int it = 0; it < 8; ++it) {
        const int idx = it * 256 + t, row = idx >> 4, kw = idx & 15;
        bd[row * 20 + kw] = bsrc[row * 128 + ks * 16 + kw];
      }
    }
    __syncthreads();
    f16x8 af = *(const f16x8*)&SMc[(16 * w + lr) * 264 + ks * 32 + lg * 8];
#pragma unroll
    for (int nt = 0; nt < 8; ++nt) {
      f16x8 bf = *(const f16x8*)&Bl[nt * 16 + lr][lg * 8];
      acc[nt] = __builtin_amdgcn_mfma_f32_16x16x32_f16(af, bf, acc[nt], 0, 0, 0);
    }
  }
  {
    float v[8][4];
#pragma unroll
    for (int nt = 0; nt < 8; ++nt) {
      const float bb = wkb[kk * 128 + nt * 16 + lr];
#pragma unroll
      for (int r = 0; r < 4; ++r) v[nt][r] = acc[nt][r] + bb;
    }
#pragma unroll
    for (int r = 0; r < 4; ++r) {
      float ss = 0.f;
#pragma unroll
      for (int nt = 0; nt < 8; ++nt) ss += v[nt][r] * v[nt][r];
      ss += __shfl_xor(ss, 1); ss += __shfl_xor(ss, 2); ss += __shfl_xor(ss, 4); ss += __shfl_xor(ss, 8);
      const float scl = 1.f / fmaxf(sqrtf(ss), 1e-12f);
#pragma unroll
      for (int nt = 0; nt < 8; ++nt)
        P[16 * w + lg * 4 + r][nt * 16 + lr] = (f16)(v[nt][r] * scl);
    }
  }
  __syncthreads();
  float m_run[4], s_run[4], pos_v[4], neg_m[4];
#pragma unroll
  for (int r = 0; r < 4; ++r) { m_run[r] = -1e30f; s_run[r] = 0.f; pos_v[r] = -1e30f; neg_m[r] = -1e30f; }
  for (int sc = 0; sc < 4; ++sc) {
    __syncthreads();
    {
      const uint32_t* zsrc = (const uint32_t*)(zf16 + ((size_t)b * 256 + sc * 64) * 128);
      uint32_t* zd = (uint32_t*)SMc;
#pragma unroll
      for (int it = 0; it < 16; ++it) {
        const int idx = it * 256 + t, row = idx >> 6, cw = idx & 63;
        zd[row * 68 + cw] = zsrc[row * 64 + cw];
      }
    }
    __syncthreads();
    f32x4 sa[4] = {};
#pragma unroll
    for (int ks = 0; ks < 4; ++ks) {
      f16x8 af = *(const f16x8*)&P[16 * w + lr][ks * 32 + lg * 8];
#pragma unroll
      for (int nt = 0; nt < 4; ++nt) {
        f16x8 bf = *(const f16x8*)&SMc[(nt * 16 + lr) * 136 + ks * 32 + lg * 8];
        sa[nt] = __builtin_amdgcn_mfma_f32_16x16x32_f16(af, bf, sa[nt], 0, 0, 0);
      }
    }
#pragma unroll
    for (int r = 0; r < 4; ++r) {
      const int trow = t0 + 16 * w + lg * 4 + r;
      const int pos_s = trow + kk + 1;
      float vv[4];
#pragma unroll
      for (int nt = 0; nt < 4; ++nt) vv[nt] = sa[nt][r] * 10.f;
      float cm = fmaxf(fmaxf(vv[0], vv[1]), fmaxf(vv[2], vv[3]));
      cm = fmaxf(cm, __shfl_xor(cm, 1)); cm = fmaxf(cm, __shfl_xor(cm, 2));
      cm = fmaxf(cm, __shfl_xor(cm, 4)); cm = fmaxf(cm, __shfl_xor(cm, 8));
      const float nm = fmaxf(m_run[r], cm);
      float ps = __expf(vv[0] - nm) + __expf(vv[1] - nm) + __expf(vv[2] - nm) + __expf(vv[3] - nm);
      ps += __shfl_xor(ps, 1); ps += __shfl_xor(ps, 2); ps += __shfl_xor(ps, 4); ps += __shfl_xor(ps, 8);
      s_run[r] = s_run[r] * __expf(m_run[r] - nm) + ps;
      m_run[r] = nm;
      const int sbase = sc * 64 + lr;
#pragma unroll
      for (int nt = 0; nt < 4; ++nt) {
        const int s = sbase + nt * 16;
        if (s == pos_s) pos_v[r] = vv[nt];
        else neg_m[r] = fmaxf(neg_m[r], vv[nt]);
      }
    }
  }
  __syncthreads();
  if (t == 0) { red[0] = 0.f; red[1] = 0.f; }
  __syncthreads();
  float lsum = 0.f, csum = 0.f;
#pragma unroll
  for (int r = 0; r < 4; ++r) {
    float pv = pos_v[r], ng = neg_m[r];
    pv = fmaxf(pv, __shfl_xor(pv, 1)); pv = fmaxf(pv, __shfl_xor(pv, 2));
    pv = fmaxf(pv, __shfl_xor(pv, 4)); pv = fmaxf(pv, __shfl_xor(pv, 8));
    ng = fmaxf(ng, __shfl_xor(ng, 1)); ng = fmaxf(ng, __shfl_xor(ng, 2));
    ng = fmaxf(ng, __shfl_xor(ng, 4)); ng = fmaxf(ng, __shfl_xor(ng, 8));
    const int trow = t0 + 16 * w + lg * 4 + r;
    if (lr == 0 && trow < 244) {
      const float lse = m_run[r] + __logf(s_run[r]);
      lsum += lse - pv;
      csum += (pv >= ng) ? 1.f : 0.f;
    }
  }
  if (lr == 0) { atomicAdd(&red[0], lsum); atomicAdd(&red[1], csum); }
  __syncthreads();
  if (t == 0) { atomicAdd(&accb[0], red[0]); atomicAdd(&accb[1], red[1]); }
}

__global__ void k_fin(const float* __restrict__ accb, float* __restrict__ out) {
  out[0] = accb[0] * (1.0f / NTOT_LOSS);
  out[1] = accb[1] * (100.0f / NTOT_LOSS);
}

// ---------------------------------------------------------------------------
extern "C" void kernel_launch(void* const* d_in, const int* in_sizes, int n_in,
                              void* d_out, int out_size, void* d_ws, size_t ws_size,
                              hipStream_t stream) {
  (void)in_sizes; (void)n_in; (void)out_size; (void)ws_size;
  const float* rr  = (const float*)d_in[0];
  const float* w1  = (const float*)d_in[1];
  const float* b1  = (const float*)d_in[2];
  const float* w2  = (const float*)d_in[3];
  const float* b2  = (const float*)d_in[4];
  const float* wih = (const float*)d_in[5];
  const float* whh = (const float*)d_in[6];
  const float* bih = (const float*)d_in[7];
  const float* bhh = (const float*)d_in[8];
  const float* wkw = (const float*)d_in[9];
  const float* wkb = (const float*)d_in[10];
  float* out = (float*)d_out;
  char* ws = (char*)d_ws;

  const size_t GX_B = (size_t)32768 * 768 * 2;  // 50,331,648 B (gxS: 48MB used)
  f16* gxS  = (f16*)ws;
  f16* h1   = (f16*)ws;  // alias: h1 dead before gxS written
  f16* zf16 = (f16*)(ws + GX_B);
  f16* cf16 = (f16*)(ws + GX_B + 8388608);
  f16* w1T  = (f16*)(ws + GX_B + 8388608 + 16777216);
  f16* w2T  = w1T + 65536;
  f16* wihF = w2T + 32768;
  f16* whhG3 = wihF + 98304;
  f16* wkT  = whhG3 + 196608;
  float* biasc = (float*)(wkT + 393216);
  float* accb  = biasc + 768;

  float* zf32 = out + 2;
  float* cf32 = out + 2 + 4194304;

  k_prep<<<256, 256, 0, stream>>>(w1, w2, wih, whh, wkw, bih, bhh,
                                  w1T, w2T, wihF, whhG3, wkT, biasc, accb);
  k_gemm64<256, true, true, false><<<dim3(512, 4), 256, 0, stream>>>(rr, w1T, b1, h1, 256);
  k_enc2<<<dim3(512), 256, 0, stream>>>(h1, w2T, b2, zf32, zf16);
  k_gemm64<128, false, false, true><<<dim3(512, 12), 256, 0, stream>>>(zf16, wihF, biasc, gxS, 768);
  k_gru<<<8, 512, 0, stream>>>(gxS, whhG3, bhh, cf16);
  k_c32<<<4096, 256, 0, stream>>>(cf16, cf32);
  k_cpc<<<dim3(4, 128, 12), 256, 0, stream>>>(cf16, zf16, wkT, wkb, accb);
  k_fin<<<1, 1, 0, stream>>>(accb, out);
}